// Round 1
// baseline (157.412 us; speedup 1.0000x reference)
//
#include <hip/hip_runtime.h>

// Problem constants (match reference setup_inputs)
#define BATCH 64
#define HH 512
#define WW 512
#define RSTRIP 32          // output rows per strip
#define LPR 128            // lanes per image row (4 output cols per lane)

__device__ __forceinline__ float4 ld4(const float* __restrict__ row, int cb) {
    // cb = column block index (16B-aligned float4). Zero outside [0,128).
    if ((unsigned)cb < (unsigned)(WW / 4)) {
        return reinterpret_cast<const float4*>(row)[cb];
    }
    return make_float4(0.f, 0.f, 0.f, 0.f);
}

// Add (sign=+1) or remove (sign=-1) one input row's 9-wide horizontal sums
// of the 5 products into the per-thread box accumulators box[5][4].
__device__ __forceinline__ void accum_row(const float* __restrict__ Ir,
                                          const float* __restrict__ Jr,
                                          int tt, float sign,
                                          float box[5][4]) {
    float4 ia = ld4(Ir, tt - 1), ib = ld4(Ir, tt), ic = ld4(Ir, tt + 1);
    float4 ja = ld4(Jr, tt - 1), jb = ld4(Jr, tt), jc = ld4(Jr, tt + 1);
    float pI[12] = {ia.x, ia.y, ia.z, ia.w, ib.x, ib.y, ib.z, ib.w,
                    ic.x, ic.y, ic.z, ic.w};
    float pJ[12] = {ja.x, ja.y, ja.z, ja.w, jb.x, jb.y, jb.z, jb.w,
                    jc.x, jc.y, jc.z, jc.w};
#pragma unroll
    for (int k = 0; k < 5; ++k) {
        float p[12];
#pragma unroll
        for (int c = 0; c < 12; ++c) {
            p[c] = (k == 0) ? pI[c]
                 : (k == 1) ? pJ[c]
                 : (k == 2) ? pI[c] * pI[c]
                 : (k == 3) ? pJ[c] * pJ[c]
                            : pI[c] * pJ[c];
        }
        // window for output col o covers local cols o..o+8
        float s = p[0];
#pragma unroll
        for (int c = 1; c < 9; ++c) s += p[c];
        box[k][0] = fmaf(sign, s, box[k][0]);
#pragma unroll
        for (int o = 1; o < 4; ++o) {
            s += p[o + 8] - p[o - 1];
            box[k][o] = fmaf(sign, s, box[k][o]);
        }
    }
}

__global__ __launch_bounds__(256) void ncc_kernel(const float* __restrict__ I,
                                                  const float* __restrict__ J,
                                                  float* __restrict__ ws) {
    const int T = threadIdx.x;
    const int tt = T & (LPR - 1);     // lane within image row: cols 4tt..4tt+3
    const int sub = T >> 7;           // which of the 2 strips in this block
    const int blk = blockIdx.x;       // 0..511
    const int b = blk >> 3;           // batch 0..63
    const int sp = blk & 7;           // strip pair 0..7
    const int r0 = (sp * 2 + sub) * RSTRIP;

    const float* Ib = I + (size_t)b * (HH * WW);
    const float* Jb = J + (size_t)b * (HH * WW);

    float box[5][4];
#pragma unroll
    for (int k = 0; k < 5; ++k)
#pragma unroll
        for (int o = 0; o < 4; ++o) box[k][o] = 0.f;

    // Warm-up: box for output row r0 covers input rows r0-4 .. r0+4
    for (int j = r0 - 4; j <= r0 + 4; ++j) {
        if (j >= 0) {  // j < HH always here (r0+4 <= 484)
            accum_row(Ib + (size_t)j * WW, Jb + (size_t)j * WW, tt, 1.f, box);
        }
    }

    const float inv81 = 1.f / 81.f;
    float acc = 0.f;
    for (int h = 0; h < RSTRIP; ++h) {
#pragma unroll
        for (int o = 0; o < 4; ++o) {
            float IS = box[0][o], JS = box[1][o];
            float I2 = box[2][o], J2 = box[3][o], IJ = box[4][o];
            float cross = IJ - IS * JS * inv81;
            float Iv = I2 - IS * IS * inv81;
            float Jv = J2 - JS * JS * inv81;
            float denom = Iv * Jv + 1e-5f;
            acc += cross * cross * __builtin_amdgcn_rcpf(denom);
        }
        if (h + 1 < RSTRIP) {
            int jl = r0 + h + 5;   // leading row entering the window
            int jt = r0 + h - 4;   // trailing row leaving the window
            if (jl < HH)
                accum_row(Ib + (size_t)jl * WW, Jb + (size_t)jl * WW, tt, 1.f, box);
            if (jt >= 0)
                accum_row(Ib + (size_t)jt * WW, Jb + (size_t)jt * WW, tt, -1.f, box);
        }
    }

    // Reduce acc across block, one atomic per block
#pragma unroll
    for (int off = 32; off; off >>= 1) acc += __shfl_down(acc, off);
    __shared__ float wpart[4];
    if ((T & 63) == 0) wpart[T >> 6] = acc;
    __syncthreads();
    if (T == 0) atomicAdd(&ws[0], wpart[0] + wpart[1] + wpart[2] + wpart[3]);
}

__global__ __launch_bounds__(256) void reg_kernel(const float* __restrict__ P,
                                                  float* __restrict__ ws) {
    const int C4 = WW / 4;                         // 128
    const size_t n4 = (size_t)BATCH * 2 * HH * C4; // 8.39M float4s
    float sdx = 0.f, sdy = 0.f;
    for (size_t i = (size_t)blockIdx.x * blockDim.x + threadIdx.x; i < n4;
         i += (size_t)gridDim.x * blockDim.x) {
        int c4 = (int)(i & (C4 - 1));
        size_t row = i >> 7;            // global row index over (B*2*H)
        int r = (int)(row & (HH - 1));  // row within image
        const float* rp = P + row * (size_t)WW;
        float4 v = reinterpret_cast<const float4*>(rp)[c4];
        float d0 = v.y - v.x, d1 = v.z - v.y, d2 = v.w - v.z;
        sdx += d0 * d0 + d1 * d1 + d2 * d2;
        if (c4 < C4 - 1) {
            float nx = rp[c4 * 4 + 4];
            float d3 = nx - v.w;
            sdx += d3 * d3;
        }
        if (r < HH - 1) {
            float4 u = reinterpret_cast<const float4*>(rp + WW)[c4];
            float e0 = u.x - v.x, e1 = u.y - v.y, e2 = u.z - v.z, e3 = u.w - v.w;
            sdy += e0 * e0 + e1 * e1 + e2 * e2 + e3 * e3;
        }
    }
#pragma unroll
    for (int off = 32; off; off >>= 1) {
        sdx += __shfl_down(sdx, off);
        sdy += __shfl_down(sdy, off);
    }
    __shared__ float px[4], py[4];
    const int T = threadIdx.x;
    if ((T & 63) == 0) { px[T >> 6] = sdx; py[T >> 6] = sdy; }
    __syncthreads();
    if (T == 0) {
        atomicAdd(&ws[1], px[0] + px[1] + px[2] + px[3]);
        atomicAdd(&ws[2], py[0] + py[1] + py[2] + py[3]);
    }
}

__global__ void finalize_kernel(const float* __restrict__ ws,
                                float* __restrict__ out) {
    float cc_sum = ws[0], dx_sum = ws[1], dy_sum = ws[2];
    float loss_sim = -(cc_sum / 16777216.f);        // 64*512*512, SIM_FACTOR=1
    float mdx = dx_sum / 33488896.f;                // 64*2*512*511
    float mdy = dy_sum / 33488896.f;                // 64*2*511*512
    float loss_reg = (mdx + mdy) * 0.5f * 0.1f;
    out[0] = loss_sim;
    out[1] = loss_reg;
    out[2] = loss_sim + loss_reg;
}

extern "C" void kernel_launch(void* const* d_in, const int* in_sizes, int n_in,
                              void* d_out, int out_size, void* d_ws, size_t ws_size,
                              hipStream_t stream) {
    const float* I = (const float*)d_in[0];   // target_proj
    const float* J = (const float*)d_in[1];   // warped_moving
    const float* P = (const float*)d_in[2];   // phi
    float* out = (float*)d_out;
    float* ws = (float*)d_ws;

    hipMemsetAsync(d_ws, 0, 3 * sizeof(float), stream);
    ncc_kernel<<<512, 256, 0, stream>>>(I, J, ws);
    reg_kernel<<<2048, 256, 0, stream>>>(P, ws);
    finalize_kernel<<<1, 1, 0, stream>>>(ws, out);
}

// Round 2
// 145.391 us; speedup vs baseline: 1.0827x; 1.0827x over previous
//
#include <hip/hip_runtime.h>

#define HH 512
#define WW 512
#define RSTRIP 16          // ncc: output rows per strip
#define NCC_BLOCKS 1024    // 2048 strips, 2 per block (2 x 128 lanes)
#define REG_BLOCKS 1024    // 2048 row-strips of 32 rows, 2 per block

// ---- 12-wide row fetch: float4s at tt-1, tt, tt+1 (zero outside image) ----
__device__ __forceinline__ void ld12(const float* __restrict__ row, int tt,
                                     float v[12]) {
    const float4* p = reinterpret_cast<const float4*>(row) + tt;
    float4 a = (tt > 0)   ? p[-1] : make_float4(0.f, 0.f, 0.f, 0.f);
    float4 b = p[0];
    float4 c = (tt < 127) ? p[1]  : make_float4(0.f, 0.f, 0.f, 0.f);
    v[0] = a.x; v[1] = a.y; v[2]  = a.z; v[3]  = a.w;
    v[4] = b.x; v[5] = b.y; v[6]  = b.z; v[7]  = b.w;
    v[8] = c.x; v[9] = c.y; v[10] = c.z; v[11] = c.w;
}

// sliding 9-window accumulate of d[0..11] into bx[0..3]
__device__ __forceinline__ void win_acc(const float d[12], float* bx) {
    float s = ((d[0] + d[1]) + (d[2] + d[3])) +
              ((d[4] + d[5]) + (d[6] + d[7])) + d[8];
    bx[0] += s;
    s += d[9]  - d[0]; bx[1] += s;
    s += d[10] - d[1]; bx[2] += s;
    s += d[11] - d[2]; bx[3] += s;
}

// One row-step update: add lead row (if HASL), subtract trail row (if HAST),
// with the difference taken at the product level so each of the 5 products
// needs only ONE sliding-window pass.
template<bool HASL, bool HAST>
__device__ __forceinline__ void upd(const float* __restrict__ Il,
                                    const float* __restrict__ Jl,
                                    const float* __restrict__ It,
                                    const float* __restrict__ Jt,
                                    int tt, float box[5][4]) {
    float li[12], lj[12], ti[12], tj[12], d[12];
    if (HASL) { ld12(Il, tt, li); ld12(Jl, tt, lj); }
    if (HAST) { ld12(It, tt, ti); ld12(Jt, tt, tj); }

    // I sum
#pragma unroll
    for (int c = 0; c < 12; ++c)
        d[c] = HASL ? (HAST ? li[c] - ti[c] : li[c]) : -ti[c];
    win_acc(d, box[0]);
    // I^2 sum
#pragma unroll
    for (int c = 0; c < 12; ++c)
        d[c] = HASL ? (HAST ? fmaf(li[c], li[c], -(ti[c] * ti[c]))
                            : li[c] * li[c])
                    : -(ti[c] * ti[c]);
    win_acc(d, box[2]);
    // I*J sum
#pragma unroll
    for (int c = 0; c < 12; ++c)
        d[c] = HASL ? (HAST ? fmaf(li[c], lj[c], -(ti[c] * tj[c]))
                            : li[c] * lj[c])
                    : -(ti[c] * tj[c]);
    win_acc(d, box[4]);
    // J sum
#pragma unroll
    for (int c = 0; c < 12; ++c)
        d[c] = HASL ? (HAST ? lj[c] - tj[c] : lj[c]) : -tj[c];
    win_acc(d, box[1]);
    // J^2 sum
#pragma unroll
    for (int c = 0; c < 12; ++c)
        d[c] = HASL ? (HAST ? fmaf(lj[c], lj[c], -(tj[c] * tj[c]))
                            : lj[c] * lj[c])
                    : -(tj[c] * tj[c]);
    win_acc(d, box[3]);
}

__device__ void ncc_body(int sbid, const float* __restrict__ I,
                         const float* __restrict__ J, float* __restrict__ ws,
                         float* sh) {
    const int T = threadIdx.x;
    const int tt = T & 127;                   // cols 4tt..4tt+3
    const int strip = (sbid << 1) | (T >> 7); // 0..2047
    const int b = strip >> 5;                 // 32 strips per image
    const int s = strip & 31;
    const int r0 = s << 4;

    const float* Ib = I + (size_t)b * (HH * WW);
    const float* Jb = J + (size_t)b * (HH * WW);

    float box[5][4];
#pragma unroll
    for (int k = 0; k < 5; ++k)
#pragma unroll
        for (int o = 0; o < 4; ++o) box[k][o] = 0.f;

    // warm-up: rows r0-4 .. r0+4 (branch is wave-uniform; only strip 0 skips)
    for (int j = r0 - 4; j <= r0 + 4; ++j) {
        if (j >= 0)
            upd<true, false>(Ib + (size_t)j * WW, Jb + (size_t)j * WW,
                             Ib, Jb, tt, box);
    }

    const float inv81 = 1.f / 81.f;
    float acc = 0.f;
    for (int h = 0; h < RSTRIP; ++h) {
#pragma unroll
        for (int o = 0; o < 4; ++o) {
            float IS = box[0][o], JS = box[1][o];
            float I2 = box[2][o], J2 = box[3][o], IJ = box[4][o];
            float cross = IJ - IS * JS * inv81;
            float Iv = I2 - IS * IS * inv81;
            float Jv = J2 - JS * JS * inv81;
            float denom = Iv * Jv + 1e-5f;
            acc += cross * cross * __builtin_amdgcn_rcpf(denom);
        }
        if (h + 1 < RSTRIP) {
            const int jl = r0 + h + 5;  // row entering the window
            const int jt = r0 + h - 4;  // row leaving the window
            const float* IlP = Ib + (size_t)jl * WW;
            const float* JlP = Jb + (size_t)jl * WW;
            const float* ItP = Ib + (size_t)jt * WW;
            const float* JtP = Jb + (size_t)jt * WW;
            if (jl < HH) {             // wave-uniform branches
                if (jt >= 0) upd<true, true>(IlP, JlP, ItP, JtP, tt, box);
                else         upd<true, false>(IlP, JlP, Ib, Jb, tt, box);
            } else if (jt >= 0) {
                upd<false, true>(Ib, Jb, ItP, JtP, tt, box);
            }
        }
    }

#pragma unroll
    for (int off = 32; off; off >>= 1) acc += __shfl_down(acc, off);
    if ((T & 63) == 0) sh[T >> 6] = acc;
    __syncthreads();
    if (T == 0) atomicAdd(&ws[0], sh[0] + sh[1] + sh[2] + sh[3]);
}

__device__ void reg_body(int sbid, const float* __restrict__ P,
                         float* __restrict__ ws, float* sh) {
    const int T = threadIdx.x;
    const int c4 = T & 127;
    const int strip = (sbid << 1) | (T >> 7);      // 0..2047 over 65536 rows
    const size_t row0 = (size_t)strip << 5;        // *32
    const bool slast = ((strip & 15) == 15);       // strip ends at image row 511
    const float* rp = P + row0 * WW + (c4 << 2);

    float sdx = 0.f, sdy = 0.f;
    float4 cur = *reinterpret_cast<const float4*>(rp);
#pragma unroll 4
    for (int i = 0; i < 32; ++i) {
        // dx within this row
        float d0 = cur.y - cur.x, d1 = cur.z - cur.y, d2 = cur.w - cur.z;
        sdx += d0 * d0 + d1 * d1 + d2 * d2;
        float nx = __shfl_down(cur.x, 1);          // lane+1's first element
        if ((c4 & 63) == 63 && c4 != 127)          // cross-wave fixup (1 lane)
            nx = *(rp + (size_t)i * WW + 4);
        if (c4 < 127) {
            float d3 = nx - cur.w;
            sdx += d3 * d3;
        }
        // dy to next row (register-carried; last row of image has none)
        if (i < 31 || !slast) {
            float4 nr = *reinterpret_cast<const float4*>(rp + (size_t)(i + 1) * WW);
            float e0 = nr.x - cur.x, e1 = nr.y - cur.y;
            float e2 = nr.z - cur.z, e3 = nr.w - cur.w;
            sdy += e0 * e0 + e1 * e1 + e2 * e2 + e3 * e3;
            cur = nr;
        }
    }

#pragma unroll
    for (int off = 32; off; off >>= 1) {
        sdx += __shfl_down(sdx, off);
        sdy += __shfl_down(sdy, off);
    }
    if ((T & 63) == 0) { sh[T >> 6] = sdx; sh[4 + (T >> 6)] = sdy; }
    __syncthreads();
    if (T == 0) {
        atomicAdd(&ws[1], sh[0] + sh[1] + sh[2] + sh[3]);
        atomicAdd(&ws[2], sh[4] + sh[5] + sh[6] + sh[7]);
    }
}

// Heterogeneous grid: odd blocks do NCC (VALU-bound), even blocks do the
// gradient reg term (HBM-bound) — co-resident waves overlap both pipes.
__global__ __launch_bounds__(256) void fused_kernel(const float* __restrict__ I,
                                                    const float* __restrict__ J,
                                                    const float* __restrict__ P,
                                                    float* __restrict__ ws) {
    __shared__ float sh[8];
    const int bid = blockIdx.x;
    if (bid & 1) ncc_body(bid >> 1, I, J, ws, sh);
    else         reg_body(bid >> 1, P, ws, sh);
}

__global__ void finalize_kernel(const float* __restrict__ ws,
                                float* __restrict__ out) {
    float cc_sum = ws[0], dx_sum = ws[1], dy_sum = ws[2];
    float loss_sim = -(cc_sum / 16777216.f);   // 64*512*512
    float mdx = dx_sum / 33488896.f;           // 64*2*512*511
    float mdy = dy_sum / 33488896.f;           // 64*2*511*512
    float loss_reg = (mdx + mdy) * 0.5f * 0.1f;
    out[0] = loss_sim;
    out[1] = loss_reg;
    out[2] = loss_sim + loss_reg;
}

extern "C" void kernel_launch(void* const* d_in, const int* in_sizes, int n_in,
                              void* d_out, int out_size, void* d_ws, size_t ws_size,
                              hipStream_t stream) {
    const float* I = (const float*)d_in[0];   // target_proj
    const float* J = (const float*)d_in[1];   // warped_moving
    const float* P = (const float*)d_in[2];   // phi
    float* out = (float*)d_out;
    float* ws = (float*)d_ws;

    hipMemsetAsync(d_ws, 0, 3 * sizeof(float), stream);
    fused_kernel<<<NCC_BLOCKS + REG_BLOCKS, 256, 0, stream>>>(I, J, P, ws);
    finalize_kernel<<<1, 1, 0, stream>>>(ws, out);
}

// Round 3
// 103.419 us; speedup vs baseline: 1.5221x; 1.4058x over previous
//
#include <hip/hip_runtime.h>

#define HH 512
#define WW 512
#define RSTRIP 16          // ncc output rows per wave-strip
#define NCC_BLOCKS 512     // 4 waves/block x 512 = 2048 strips
#define REG_BLOCKS 512     // 2 half-block strips of 64 rows -> 1024 strips

// ---- load own 8 columns (32B) of one row ----
__device__ __forceinline__ void ldrow8(const float* __restrict__ row, int lane,
                                       float v[8]) {
    const float4* p = reinterpret_cast<const float4*>(row) + (lane << 1);
    float4 a = p[0], b = p[1];
    v[0] = a.x; v[1] = a.y; v[2] = a.z; v[3] = a.w;
    v[4] = b.x; v[5] = b.y; v[6] = b.z; v[7] = b.w;
}

// ---- 9-wide sliding-window fold of d[0..7] (+intra-wave halo) into B[0..7] ----
__device__ __forceinline__ void fold(const float d[8], int lane, float* B) {
    float hl0 = __shfl_up(d[4], 1), hl1 = __shfl_up(d[5], 1);
    float hl2 = __shfl_up(d[6], 1), hl3 = __shfl_up(d[7], 1);
    float hr0 = __shfl_down(d[0], 1), hr1 = __shfl_down(d[1], 1);
    float hr2 = __shfl_down(d[2], 1), hr3 = __shfl_down(d[3], 1);
    hl0 = lane ? hl0 : 0.f; hl1 = lane ? hl1 : 0.f;
    hl2 = lane ? hl2 : 0.f; hl3 = lane ? hl3 : 0.f;
    bool nr = (lane != 63);
    hr0 = nr ? hr0 : 0.f; hr1 = nr ? hr1 : 0.f;
    hr2 = nr ? hr2 : 0.f; hr3 = nr ? hr3 : 0.f;

    float s = ((hl0 + hl1) + (hl2 + hl3)) +
              ((d[0] + d[1]) + (d[2] + d[3])) + d[4];
    B[0] += s;
    s += d[5] - hl0;  B[1] += s;
    s += d[6] - hl1;  B[2] += s;
    s += d[7] - hl2;  B[3] += s;
    s += hr0 - hl3;   B[4] += s;
    s += hr1 - d[0];  B[5] += s;
    s += hr2 - d[1];  B[6] += s;
    s += hr3 - d[2];  B[7] += s;
}

// One row-step: add lead row (HASL), remove trail row (HAST); product-level diff.
template<bool HASL, bool HAST>
__device__ __forceinline__ void upd8(const float* __restrict__ Il,
                                     const float* __restrict__ Jl,
                                     const float* __restrict__ It,
                                     const float* __restrict__ Jt,
                                     int lane, float B[5][8]) {
    float LI[8], LJ[8], TI[8], TJ[8], d[8];
    if (HASL) { ldrow8(Il, lane, LI); ldrow8(Jl, lane, LJ); }
    if (HAST) { ldrow8(It, lane, TI); ldrow8(Jt, lane, TJ); }

#pragma unroll
    for (int c = 0; c < 8; ++c)
        d[c] = HASL ? (HAST ? LI[c] - TI[c] : LI[c]) : -TI[c];
    fold(d, lane, B[0]);
#pragma unroll
    for (int c = 0; c < 8; ++c)
        d[c] = HASL ? (HAST ? LJ[c] - TJ[c] : LJ[c]) : -TJ[c];
    fold(d, lane, B[1]);
#pragma unroll
    for (int c = 0; c < 8; ++c)
        d[c] = HASL ? (HAST ? fmaf(LI[c], LI[c], -(TI[c] * TI[c]))
                            : LI[c] * LI[c])
                    : -(TI[c] * TI[c]);
    fold(d, lane, B[2]);
#pragma unroll
    for (int c = 0; c < 8; ++c)
        d[c] = HASL ? (HAST ? fmaf(LJ[c], LJ[c], -(TJ[c] * TJ[c]))
                            : LJ[c] * LJ[c])
                    : -(TJ[c] * TJ[c]);
    fold(d, lane, B[3]);
#pragma unroll
    for (int c = 0; c < 8; ++c)
        d[c] = HASL ? (HAST ? fmaf(LI[c], LJ[c], -(TI[c] * TJ[c]))
                            : LI[c] * LJ[c])
                    : -(TI[c] * TJ[c]);
    fold(d, lane, B[4]);
}

__device__ void ncc_body(int sbid, const float* __restrict__ I,
                         const float* __restrict__ J, float* __restrict__ ws,
                         float* sh) {
    const int T = threadIdx.x;
    const int lane = T & 63;
    const int strip = (sbid << 2) | (T >> 6);   // 1 strip per wave, 0..2047
    const int b = strip >> 5;                   // 32 strips per image
    const int s = strip & 31;
    const int r0 = s << 4;

    const float* Ib = I + (size_t)b * (HH * WW);
    const float* Jb = J + (size_t)b * (HH * WW);

    float B[5][8];
#pragma unroll
    for (int k = 0; k < 5; ++k)
#pragma unroll
        for (int o = 0; o < 8; ++o) B[k][o] = 0.f;

    // warm-up: rows r0-4 .. r0+4 (wave-uniform skip below image top)
    for (int j = r0 - 4; j <= r0 + 4; ++j) {
        if (j >= 0)
            upd8<true, false>(Ib + (size_t)j * WW, Jb + (size_t)j * WW,
                              Ib, Jb, lane, B);
    }

    const float inv81 = 1.f / 81.f;
    float acc = 0.f;
    for (int h = 0;; ++h) {
#pragma unroll
        for (int o = 0; o < 8; ++o) {
            float IS = B[0][o], JS = B[1][o];
            float I2 = B[2][o], J2 = B[3][o], IJ = B[4][o];
            float cross = fmaf(-(IS * JS), inv81, IJ);
            float Iv = fmaf(-(IS * IS), inv81, I2);
            float Jv = fmaf(-(JS * JS), inv81, J2);
            float denom = fmaf(Iv, Jv, 1e-5f);
            acc = fmaf(cross * cross, __builtin_amdgcn_rcpf(denom), acc);
        }
        if (h == RSTRIP - 1) break;
        const int jl = r0 + h + 5;   // row entering window for output row r0+h+1
        const int jt = r0 + h - 4;   // row leaving window
        const float* IlP = Ib + (size_t)jl * WW;
        const float* JlP = Jb + (size_t)jl * WW;
        const float* ItP = Ib + (size_t)jt * WW;
        const float* JtP = Jb + (size_t)jt * WW;
        if (jl < HH) {               // wave-uniform
            if (jt >= 0) upd8<true, true>(IlP, JlP, ItP, JtP, lane, B);
            else         upd8<true, false>(IlP, JlP, Ib, Jb, lane, B);
        } else if (jt >= 0) {
            upd8<false, true>(Ib, Jb, ItP, JtP, lane, B);
        }
    }

#pragma unroll
    for (int off = 32; off; off >>= 1) acc += __shfl_down(acc, off);
    if ((T & 63) == 0) sh[T >> 6] = acc;
    __syncthreads();
    if (T == 0) atomicAdd(&ws[0], sh[0] + sh[1] + sh[2] + sh[3]);
}

__device__ void reg_body(int sbid, const float* __restrict__ P,
                         float* __restrict__ ws, float* sh) {
    const int T = threadIdx.x;
    const int c4 = T & 127;                    // 128 float4s = one row
    const int strip = (sbid << 1) | (T >> 7);  // 0..1023 over 65536 rows
    const size_t row0 = (size_t)strip << 6;    // *64 rows per strip
    const bool slast = ((strip & 7) == 7);     // strip ends at image row 511
    const float* rp = P + row0 * WW + (c4 << 2);

    float sdx = 0.f, sdy = 0.f;
    float4 cur = *reinterpret_cast<const float4*>(rp);
#pragma unroll 8
    for (int i = 0; i < 64; ++i) {
        float d0 = cur.y - cur.x, d1 = cur.z - cur.y, d2 = cur.w - cur.z;
        sdx += d0 * d0 + d1 * d1 + d2 * d2;
        if (c4 < 127) {                        // neighbor's first elem (L1-hit)
            float nx = rp[(size_t)i * WW + 4];
            float d3 = nx - cur.w;
            sdx += d3 * d3;
        }
        if (i < 63) {
            float4 nr = *reinterpret_cast<const float4*>(rp + (size_t)(i + 1) * WW);
            float e0 = nr.x - cur.x, e1 = nr.y - cur.y;
            float e2 = nr.z - cur.z, e3 = nr.w - cur.w;
            sdy += e0 * e0 + e1 * e1 + e2 * e2 + e3 * e3;
            cur = nr;
        } else if (!slast) {                   // dy from last strip row to next
            float4 nr = *reinterpret_cast<const float4*>(rp + (size_t)64 * WW);
            float e0 = nr.x - cur.x, e1 = nr.y - cur.y;
            float e2 = nr.z - cur.z, e3 = nr.w - cur.w;
            sdy += e0 * e0 + e1 * e1 + e2 * e2 + e3 * e3;
        }
    }

#pragma unroll
    for (int off = 32; off; off >>= 1) {
        sdx += __shfl_down(sdx, off);
        sdy += __shfl_down(sdy, off);
    }
    if ((T & 63) == 0) { sh[T >> 6] = sdx; sh[4 + (T >> 6)] = sdy; }
    __syncthreads();
    if (T == 0) {
        atomicAdd(&ws[1], sh[0] + sh[1] + sh[2] + sh[3]);
        atomicAdd(&ws[2], sh[4] + sh[5] + sh[6] + sh[7]);
    }
}

// Heterogeneous grid: odd blocks = NCC (VALU/latency), even = reg (HBM stream).
__global__ __launch_bounds__(256) void fused_kernel(const float* __restrict__ I,
                                                    const float* __restrict__ J,
                                                    const float* __restrict__ P,
                                                    float* __restrict__ ws) {
    __shared__ float sh[8];
    const int bid = blockIdx.x;
    if (bid & 1) ncc_body(bid >> 1, I, J, ws, sh);
    else         reg_body(bid >> 1, P, ws, sh);
}

__global__ void finalize_kernel(const float* __restrict__ ws,
                                float* __restrict__ out) {
    float cc_sum = ws[0], dx_sum = ws[1], dy_sum = ws[2];
    float loss_sim = -(cc_sum / 16777216.f);   // 64*512*512
    float mdx = dx_sum / 33488896.f;           // 64*2*512*511
    float mdy = dy_sum / 33488896.f;           // 64*2*511*512
    float loss_reg = (mdx + mdy) * 0.5f * 0.1f;
    out[0] = loss_sim;
    out[1] = loss_reg;
    out[2] = loss_sim + loss_reg;
}

extern "C" void kernel_launch(void* const* d_in, const int* in_sizes, int n_in,
                              void* d_out, int out_size, void* d_ws, size_t ws_size,
                              hipStream_t stream) {
    const float* I = (const float*)d_in[0];   // target_proj
    const float* J = (const float*)d_in[1];   // warped_moving
    const float* P = (const float*)d_in[2];   // phi
    float* out = (float*)d_out;
    float* ws = (float*)d_ws;

    hipMemsetAsync(d_ws, 0, 3 * sizeof(float), stream);
    fused_kernel<<<NCC_BLOCKS + REG_BLOCKS, 256, 0, stream>>>(I, J, P, ws);
    finalize_kernel<<<1, 1, 0, stream>>>(ws, out);
}

// Round 4
// 99.760 us; speedup vs baseline: 1.5779x; 1.0367x over previous
//
#include <hip/hip_runtime.h>

#define HH 512
#define WW 512
#define RSTRIP 16          // ncc output rows per wave-strip
#define NCC_BLOCKS 512     // 4 waves/block -> 2048 strips
#define REG_BLOCKS 512     // 1024 strips of 64 rows

// Load 16 consecutive floats (cols 8*lane-4 .. 8*lane+11) of one row.
// OOB column blocks (lane 0 left, lane 63 right) return zeros; addresses
// are clamped (branchless per-lane select) so no exec-mask divergence.
__device__ __forceinline__ void ld16(const float* __restrict__ row, int lane,
                                     float v[16]) {
    const float4* p = reinterpret_cast<const float4*>(row);
    const int b0 = (lane << 1) - 1;          // -1 .. 125
    float4 a = p[b0 < 0 ? 0 : b0];
    float4 b = p[b0 + 1];
    float4 c = p[b0 + 2];
    float4 e = p[b0 + 3 > 127 ? 127 : b0 + 3];
    if (b0 < 0)       a = make_float4(0.f, 0.f, 0.f, 0.f);
    if (b0 + 3 > 127) e = make_float4(0.f, 0.f, 0.f, 0.f);
    v[0]  = a.x; v[1]  = a.y; v[2]  = a.z; v[3]  = a.w;
    v[4]  = b.x; v[5]  = b.y; v[6]  = b.z; v[7]  = b.w;
    v[8]  = c.x; v[9]  = c.y; v[10] = c.z; v[11] = c.w;
    v[12] = e.x; v[13] = e.y; v[14] = e.z; v[15] = e.w;
}

// Load I-row and J-row with row-index clamp; rows outside [0,511] yield zeros
// (correct zero-padding semantics for the box window). Uniform branch.
__device__ __forceinline__ void ld_rows(const float* __restrict__ Ib,
                                        const float* __restrict__ Jb,
                                        int row, int lane,
                                        float vi[16], float vj[16]) {
    const int rc = row < 0 ? 0 : (row > HH - 1 ? HH - 1 : row);
    ld16(Ib + (size_t)rc * WW, lane, vi);
    ld16(Jb + (size_t)rc * WW, lane, vj);
    if (rc != row) {
#pragma unroll
        for (int i = 0; i < 16; ++i) { vi[i] = 0.f; vj[i] = 0.f; }
    }
}

// 9-wide sliding-window fold of d[0..15] into B[0..7] (outputs cols 8l..8l+7).
__device__ __forceinline__ void fold16(const float d[16], float* B) {
    float s = (((d[0] + d[1]) + (d[2] + d[3])) +
               ((d[4] + d[5]) + (d[6] + d[7]))) + d[8];
    B[0] += s;
#pragma unroll
    for (int o = 1; o < 8; ++o) {
        s += d[o + 8] - d[o - 1];
        B[o] += s;
    }
}

// Warm-up: add one row's products.
__device__ __forceinline__ void acc_lead(const float LI[16], const float LJ[16],
                                         float B[5][8]) {
    float d[16];
    fold16(LI, B[0]);
    fold16(LJ, B[1]);
#pragma unroll
    for (int i = 0; i < 16; ++i) d[i] = LI[i] * LI[i];
    fold16(d, B[2]);
#pragma unroll
    for (int i = 0; i < 16; ++i) d[i] = LJ[i] * LJ[i];
    fold16(d, B[3]);
#pragma unroll
    for (int i = 0; i < 16; ++i) d[i] = LI[i] * LJ[i];
    fold16(d, B[4]);
}

// Steady: add lead row, remove trail row (product-level difference).
__device__ __forceinline__ void acc_diff(const float LI[16], const float LJ[16],
                                         const float TI[16], const float TJ[16],
                                         float B[5][8]) {
    float d[16];
#pragma unroll
    for (int i = 0; i < 16; ++i) d[i] = LI[i] - TI[i];
    fold16(d, B[0]);
#pragma unroll
    for (int i = 0; i < 16; ++i) d[i] = LJ[i] - TJ[i];
    fold16(d, B[1]);
#pragma unroll
    for (int i = 0; i < 16; ++i) d[i] = fmaf(LI[i], LI[i], -(TI[i] * TI[i]));
    fold16(d, B[2]);
#pragma unroll
    for (int i = 0; i < 16; ++i) d[i] = fmaf(LJ[i], LJ[i], -(TJ[i] * TJ[i]));
    fold16(d, B[3]);
#pragma unroll
    for (int i = 0; i < 16; ++i) d[i] = fmaf(LI[i], LJ[i], -(TI[i] * TJ[i]));
    fold16(d, B[4]);
}

__device__ __forceinline__ float cc_row(const float B[5][8]) {
    const float inv81 = 1.f / 81.f;
    float a = 0.f;
#pragma unroll
    for (int o = 0; o < 8; ++o) {
        float IS = B[0][o], JS = B[1][o];
        float I2 = B[2][o], J2 = B[3][o], IJ = B[4][o];
        float cross = fmaf(-(IS * JS), inv81, IJ);
        float Iv = fmaf(-(IS * IS), inv81, I2);
        float Jv = fmaf(-(JS * JS), inv81, J2);
        float denom = fmaf(Iv, Jv, 1e-5f);
        a = fmaf(cross * cross, __builtin_amdgcn_rcpf(denom), a);
    }
    return a;
}

__device__ void ncc_body(int sbid, const float* __restrict__ I,
                         const float* __restrict__ J, float* __restrict__ ws,
                         float* sh) {
    const int T = threadIdx.x;
    const int lane = T & 63;
    const int strip = (sbid << 2) | (T >> 6);   // one strip per wave
    const int b = strip >> 5;                   // 32 strips per image
    const int r0 = (strip & 31) << 4;

    const float* Ib = I + (size_t)b * (HH * WW);
    const float* Jb = J + (size_t)b * (HH * WW);

    float B[5][8];
#pragma unroll
    for (int k = 0; k < 5; ++k)
#pragma unroll
        for (int o = 0; o < 8; ++o) B[k][o] = 0.f;

    // warm-up: rows r0-4 .. r0+4 (uniform skip above image top)
    {
        float vi[16], vj[16];
        for (int j = r0 - 4; j <= r0 + 4; ++j) {
            if (j >= 0) {
                ld16(Ib + (size_t)j * WW, lane, vi);
                ld16(Jb + (size_t)j * WW, lane, vj);
                acc_lead(vi, vj, B);
            }
        }
    }

    // lead-row double buffer, 1 step ahead
    float LAi[16], LAj[16], LBi[16], LBj[16];
    ld_rows(Ib, Jb, r0 + 5, lane, LAi, LAj);   // lead for step h=0 (always valid)

    float acc = 0.f;
    for (int k = 0; k < 8; ++k) {              // 2 row-steps per iteration
        {   // phase A: h = 2k (lead in LA, prefetch into LB)
            const int h = 2 * k;
            acc += cc_row(B);                  // output row r0+h
            float TI[16], TJ[16];
            ld_rows(Ib, Jb, r0 + h - 4, lane, TI, TJ);       // trail (L2-hot)
            ld_rows(Ib, Jb, r0 + h + 6, lane, LBi, LBj);     // next lead
            acc_diff(LAi, LAj, TI, TJ, B);
        }
        {   // phase B: h = 2k+1 (lead in LB, prefetch into LA)
            const int h = 2 * k + 1;
            acc += cc_row(B);                  // output row r0+h
            if (h < RSTRIP - 1) {              // uniform; false only at h=15
                float TI[16], TJ[16];
                ld_rows(Ib, Jb, r0 + h - 4, lane, TI, TJ);
                ld_rows(Ib, Jb, r0 + h + 6, lane, LAi, LAj);
                acc_diff(LBi, LBj, TI, TJ, B);
            }
        }
    }

#pragma unroll
    for (int off = 32; off; off >>= 1) acc += __shfl_down(acc, off);
    if ((T & 63) == 0) sh[T >> 6] = acc;
    __syncthreads();
    if (T == 0) atomicAdd(&ws[0], sh[0] + sh[1] + sh[2] + sh[3]);
}

__device__ void reg_body(int sbid, const float* __restrict__ P,
                         float* __restrict__ ws, float* sh) {
    const int T = threadIdx.x;
    const int c4 = T & 127;                    // 128 float4s = one row
    const int strip = (sbid << 1) | (T >> 7);  // 0..1023 over 65536 rows
    const size_t row0 = (size_t)strip << 6;    // *64 rows per strip
    const bool slast = ((strip & 7) == 7);     // strip ends at image row 511
    const float* rp = P + row0 * WW + (c4 << 2);

    float sdx = 0.f, sdy = 0.f;
    float4 cur = *reinterpret_cast<const float4*>(rp);
#pragma unroll 8
    for (int i = 0; i < 64; ++i) {
        float d0 = cur.y - cur.x, d1 = cur.z - cur.y, d2 = cur.w - cur.z;
        sdx += d0 * d0 + d1 * d1 + d2 * d2;
        if (c4 < 127) {                        // neighbor's first elem (L1-hit)
            float nx = rp[(size_t)i * WW + 4];
            float d3 = nx - cur.w;
            sdx += d3 * d3;
        }
        if (i < 63) {
            float4 nr = *reinterpret_cast<const float4*>(rp + (size_t)(i + 1) * WW);
            float e0 = nr.x - cur.x, e1 = nr.y - cur.y;
            float e2 = nr.z - cur.z, e3 = nr.w - cur.w;
            sdy += e0 * e0 + e1 * e1 + e2 * e2 + e3 * e3;
            cur = nr;
        } else if (!slast) {                   // dy last strip row -> next strip
            float4 nr = *reinterpret_cast<const float4*>(rp + (size_t)64 * WW);
            float e0 = nr.x - cur.x, e1 = nr.y - cur.y;
            float e2 = nr.z - cur.z, e3 = nr.w - cur.w;
            sdy += e0 * e0 + e1 * e1 + e2 * e2 + e3 * e3;
        }
    }

#pragma unroll
    for (int off = 32; off; off >>= 1) {
        sdx += __shfl_down(sdx, off);
        sdy += __shfl_down(sdy, off);
    }
    if ((T & 63) == 0) { sh[T >> 6] = sdx; sh[4 + (T >> 6)] = sdy; }
    __syncthreads();
    if (T == 0) {
        atomicAdd(&ws[1], sh[0] + sh[1] + sh[2] + sh[3]);
        atomicAdd(&ws[2], sh[4] + sh[5] + sh[6] + sh[7]);
    }
}

// Heterogeneous grid: odd blocks = NCC (VALU/latency), even = reg (HBM stream).
__global__ __launch_bounds__(256) void fused_kernel(const float* __restrict__ I,
                                                    const float* __restrict__ J,
                                                    const float* __restrict__ P,
                                                    float* __restrict__ ws) {
    __shared__ float sh[8];
    const int bid = blockIdx.x;
    if (bid & 1) ncc_body(bid >> 1, I, J, ws, sh);
    else         reg_body(bid >> 1, P, ws, sh);
}

__global__ void finalize_kernel(const float* __restrict__ ws,
                                float* __restrict__ out) {
    float cc_sum = ws[0], dx_sum = ws[1], dy_sum = ws[2];
    float loss_sim = -(cc_sum / 16777216.f);   // 64*512*512
    float mdx = dx_sum / 33488896.f;           // 64*2*512*511
    float mdy = dy_sum / 33488896.f;           // 64*2*511*512
    float loss_reg = (mdx + mdy) * 0.5f * 0.1f;
    out[0] = loss_sim;
    out[1] = loss_reg;
    out[2] = loss_sim + loss_reg;
}

extern "C" void kernel_launch(void* const* d_in, const int* in_sizes, int n_in,
                              void* d_out, int out_size, void* d_ws, size_t ws_size,
                              hipStream_t stream) {
    const float* I = (const float*)d_in[0];   // target_proj
    const float* J = (const float*)d_in[1];   // warped_moving
    const float* P = (const float*)d_in[2];   // phi
    float* out = (float*)d_out;
    float* ws = (float*)d_ws;

    hipMemsetAsync(d_ws, 0, 3 * sizeof(float), stream);
    fused_kernel<<<NCC_BLOCKS + REG_BLOCKS, 256, 0, stream>>>(I, J, P, ws);
    finalize_kernel<<<1, 1, 0, stream>>>(ws, out);
}